// Round 11
// baseline (98.711 us; speedup 1.0000x reference)
//
#include <hip/hip_runtime.h>
#include <math.h>

// TopKSoftMax: rows of D=64 f32; keep top-8 (ties -> lower index, exactly as
// jax.lax.top_k), softmax over kept, zeros elsewhere.
//
// R11: VALU-lean decision probe on top of R10's NT-store structure.
//  - med3 insert: s0=max(t0,x); s_i=med3(t_{i-1},t_i,x) -> 8 independent ops
//    per insert (was 15 serial).
//  - 32 elem/lane (2 lanes/row, 32-row tiles): ONE xor32 merge, no cleanup
//    sort (thr/m/sum/counts are order-free on the merged multiset).
//  - fast PROC: B = m + log(sum); o = (x>=thr) ? exp(x-B) : 0. No div, no
//    serial quota chain. Exact because (C==q && !sat) => every ==thr element
//    is kept: a lane can only undercount ties if its t7==thr (sat), since no
//    lane can hold 8 elements > thr (thr is the union's 8th largest).
//    Rare excess-tie rows take a sequential slow path under __any().
//  - geometry: 8 KB tile/wave, 2-wave blocks, launch_bounds(128,5) ->
//    10 blocks/CU = 20 waves/CU (LDS-exact: 10 x 16 KB = 160 KB).
//
// LDS slot(r,k) = r*16 + (k ^ (r&15)), float4 units; stage/read/PROC/out all
// at the structural 8-lanes-per-bank-quad minimum (verified R4-R10).

#define D4 16
#define ROWS 32
#define TILE_F4 (ROWS * D4)        // 512 float4 = 8 KB
#define WAVES 2
#define THREADS (WAVES * 64)       // 128

typedef float nfloat4 __attribute__((ext_vector_type(4)));

// med3 insert of x into sorted-desc t0>=..>=t7 (keeps top-8 of the 9-multiset)
#define INS(xx) { \
    const float _x = (xx); \
    const float n0 = fmaxf(t0, _x); \
    const float n1 = __builtin_amdgcn_fmed3f(t0, t1, _x); \
    const float n2 = __builtin_amdgcn_fmed3f(t1, t2, _x); \
    const float n3 = __builtin_amdgcn_fmed3f(t2, t3, _x); \
    const float n4 = __builtin_amdgcn_fmed3f(t3, t4, _x); \
    const float n5 = __builtin_amdgcn_fmed3f(t4, t5, _x); \
    const float n6 = __builtin_amdgcn_fmed3f(t5, t6, _x); \
    const float n7 = __builtin_amdgcn_fmed3f(t6, t7, _x); \
    t0 = n0; t1 = n1; t2 = n2; t3 = n3; t4 = n4; t5 = n5; t6 = n6; t7 = n7; }

// fast path: all ==thr elements kept
#define PROCF(x, o) { (o) = ((x) >= thr) ? __expf((x) - B) : 0.0f; }
// slow path: index-ordered tie quota
#define PROCS(x, o) { \
    const int _k = ((x) == thr) & (quota > 0); \
    quota -= _k; \
    (o) = (((x) > thr) | _k) ? __expf((x) - B) : 0.0f; }

// legacy chain (tail kernel only)
#define LVL(ti) { const float _hi = fmaxf(ti, _a); _a = fminf(ti, _a); ti = _hi; }
#define INSERT(x) { float _a = (x); \
    LVL(t0) LVL(t1) LVL(t2) LVL(t3) LVL(t4) LVL(t5) LVL(t6) \
    t7 = fmaxf(t7, _a); }
#define PROC(x, o) { \
    const int _kgt = ((x) > thr); \
    const int _keq = ((x) == thr) & (quota > 0); \
    quota -= _keq; \
    (o) = (_kgt | _keq) ? __expf((x) - m) * inv : 0.0f; }

__device__ __forceinline__ void gload_lds16(const void* g, void* l) {
    __builtin_amdgcn_global_load_lds(
        (__attribute__((address_space(1))) void*)(g),
        (__attribute__((address_space(3))) void*)(l),
        16, 0, 0);   // 16B/lane -> global_load_lds_dwordx4
}

__global__ __launch_bounds__(THREADS, 5)   // 5 waves/EU -> 10 blocks/CU (20 waves)
void topk_softmax_kernel(const float* __restrict__ in,
                         float* __restrict__ out,
                         int ntiles)
{
    __shared__ float4 tile_[WAVES][TILE_F4];   // 8 KB per wave, private

    const int lane = threadIdx.x & 63;
    const int wid  = threadIdx.x >> 6;
    const int w = blockIdx.x * WAVES + wid;    // one 32-row tile per wave
    if (w >= ntiles) return;
    float4* tile = tile_[wid];

    const float4* __restrict__ p = reinterpret_cast<const float4*>(in) + (long long)w * TILE_F4;
    float4* __restrict__ q       = reinterpret_cast<float4*>(out)      + (long long)w * TILE_F4;

    const int g = lane >> 4;          // 0..3
    const int s = lane & 15;

    // ---- stage: 8x global_load_lds_dwordx4, source pre-swizzled so linear
    //      LDS dest = swizzled tile: slot r*16+(k^(r&15)) <- (row r, quad k) ----
    #pragma unroll
    for (int c = 0; c < 8; ++c) {
        const int r = c * 4 + g;
        gload_lds16(p + r * 16 + (s ^ (r & 15)), tile + c * 64);
    }
    asm volatile("s_waitcnt vmcnt(0)" ::: "memory");

    // ---- own half-row -> regs: row r, quads [8h, 8h+8) ----
    const int r  = lane & 31;
    const int h  = lane >> 5;          // element range [h*32, h*32+32)
    const int rk = r & 15;
    int slot[8];
    float4 v[8];
    #pragma unroll
    for (int j = 0; j < 8; ++j) {
        slot[j] = r * 16 + ((8 * h + j) ^ rk);
        v[j] = tile[slot[j]];
    }

    // ---- per-lane top-8 of 32 via med3 inserts ----
    float t0 = -INFINITY, t1 = -INFINITY, t2 = -INFINITY, t3 = -INFINITY,
          t4 = -INFINITY, t5 = -INFINITY, t6 = -INFINITY, t7 = -INFINITY;
    #pragma unroll
    for (int j = 0; j < 8; ++j) {
        INS(v[j].x) INS(v[j].y) INS(v[j].z) INS(v[j].w)
    }

    // ---- single xor32 bitonic max-merge: top-8 multiset of the row ----
    const float p0 = __shfl_xor(t0, 32), p1 = __shfl_xor(t1, 32),
                p2 = __shfl_xor(t2, 32), p3 = __shfl_xor(t3, 32),
                p4 = __shfl_xor(t4, 32), p5 = __shfl_xor(t5, 32),
                p6 = __shfl_xor(t6, 32), p7 = __shfl_xor(t7, 32);
    const float c0 = fmaxf(t0, p7), c1 = fmaxf(t1, p6), c2 = fmaxf(t2, p5),
                c3 = fmaxf(t3, p4), c4 = fmaxf(t4, p3), c5 = fmaxf(t5, p2),
                c6 = fmaxf(t6, p1), c7 = fmaxf(t7, p0);
    const float m   = fmaxf(t0, p0);                                   // row max
    const float thr = fminf(fminf(fminf(c0, c1), fminf(c2, c3)),
                            fminf(fminf(c4, c5), fminf(c6, c7)));      // 8th largest
    const int cnt_gt = (c0 > thr) + (c1 > thr) + (c2 > thr) + (c3 > thr) +
                       (c4 > thr) + (c5 > thr) + (c6 > thr) + (c7 > thr);
    const float sum = __expf(c0 - m) + __expf(c1 - m) + __expf(c2 - m) + __expf(c3 - m) +
                      __expf(c4 - m) + __expf(c5 - m) + __expf(c6 - m) + __expf(c7 - m);
    const float B = m + __logf(sum);   // exp(x-m)/sum == exp(x-B)

    // ---- fast/slow tie decision (row-uniform: thr/cnt_gt identical in pair) ----
    const int ce8 = (t0 == thr) + (t1 == thr) + (t2 == thr) + (t3 == thr) +
                    (t4 == thr) + (t5 == thr) + (t6 == thr) + (t7 == thr);
    const int flags = ce8 | ((t7 == thr) ? 256 : 0);     // bit8 = saturation
    const int pf  = __shfl_xor(flags, 32);
    const int C   = (flags & 255) + (pf & 255);
    const int sat = (flags | pf) >> 8;
    const int qrow = 8 - cnt_gt;
    const bool slow = (C != qrow) || sat;

    // ---- fast PROC: write outputs back to the same swizzled slots ----
    #pragma unroll
    for (int j = 0; j < 8; ++j) {
        float4 o;
        PROCF(v[j].x, o.x) PROCF(v[j].y, o.y) PROCF(v[j].z, o.z) PROCF(v[j].w, o.w)
        tile[slot[j]] = o;
    }

    // ---- rare exact slow path (excess ties): sequential quota, true counts ----
    if (__any(slow)) {
        if (slow) {
            int my_eq = 0;
            #pragma unroll
            for (int j = 0; j < 8; ++j)
                my_eq += (v[j].x == thr) + (v[j].y == thr) +
                         (v[j].z == thr) + (v[j].w == thr);
            const int peq = __shfl_xor(my_eq, 32);       // partner active (row-uniform)
            int quota = qrow - (h ? peq : 0);            // h=1 consumes after h=0
            #pragma unroll
            for (int j = 0; j < 8; ++j) {
                float4 o;
                PROCS(v[j].x, o.x) PROCS(v[j].y, o.y)
                PROCS(v[j].z, o.z) PROCS(v[j].w, o.w)
                tile[slot[j]] = o;
            }
        }
    }
    asm volatile("s_waitcnt lgkmcnt(0)" ::: "memory");   // cross-lane reuse below

    // ---- coalesced NT out: flat F=c*64+lane lives at r*16+((lane&15)^(r&15)) ----
    #pragma unroll
    for (int c = 0; c < 8; ++c) {
        const int rr = c * 4 + g;
        const float4 o = tile[rr * 16 + (s ^ (rr & 15))];
        nfloat4 no; no.x = o.x; no.y = o.y; no.z = o.z; no.w = o.w;
        __builtin_nontemporal_store(no,
            reinterpret_cast<nfloat4*>(q + c * 64 + lane));
    }
}

// remainder rows (nrows % 32) — not taken at this problem size
__global__ __launch_bounds__(64)
void topk_softmax_tail(const float* __restrict__ in, float* __restrict__ out,
                       long long row0, long long nrows)
{
    const long long row = row0 + threadIdx.x;
    if (row >= nrows) return;
    const float4* __restrict__ p = reinterpret_cast<const float4*>(in) + row * D4;
    float4* __restrict__ q       = reinterpret_cast<float4*>(out)      + row * D4;
    float4 v[D4];
    #pragma unroll
    for (int c = 0; c < D4; ++c) v[c] = p[c];
    float t0 = -INFINITY, t1 = -INFINITY, t2 = -INFINITY, t3 = -INFINITY,
          t4 = -INFINITY, t5 = -INFINITY, t6 = -INFINITY, t7 = -INFINITY;
    #pragma unroll
    for (int c = 0; c < D4; ++c) {
        INSERT(v[c].x) INSERT(v[c].y) INSERT(v[c].z) INSERT(v[c].w)
    }
    const float thr = t7;
    const float m   = t0;
    int quota = 8 - ((t0 > thr) + (t1 > thr) + (t2 > thr) + (t3 > thr) +
                     (t4 > thr) + (t5 > thr) + (t6 > thr));
    const float sum = __expf(t0 - m) + __expf(t1 - m) + __expf(t2 - m) + __expf(t3 - m) +
                      __expf(t4 - m) + __expf(t5 - m) + __expf(t6 - m) + __expf(t7 - m);
    const float inv = 1.0f / sum;
    #pragma unroll
    for (int c = 0; c < D4; ++c) {
        float4 o;
        PROC(v[c].x, o.x) PROC(v[c].y, o.y) PROC(v[c].z, o.z) PROC(v[c].w, o.w)
        q[c] = o;
    }
}

extern "C" void kernel_launch(void* const* d_in, const int* in_sizes, int n_in,
                              void* d_out, int out_size, void* d_ws, size_t ws_size,
                              hipStream_t stream) {
    const float* in = (const float*)d_in[0];
    float* out = (float*)d_out;
    const long long nrows = in_sizes[0] / 64;
    const int ntiles = (int)(nrows / ROWS);
    const long long rem = nrows - (long long)ntiles * ROWS;

    if (ntiles > 0) {
        const int nblocks = (ntiles + WAVES - 1) / WAVES;
        topk_softmax_kernel<<<nblocks, THREADS, 0, stream>>>(in, out, ntiles);
    }
    if (rem > 0) {
        topk_softmax_tail<<<1, 64, 0, stream>>>(in, out, (long long)ntiles * ROWS, nrows);
    }
}

// Round 12
// 83.527 us; speedup vs baseline: 1.1818x; 1.1818x over previous
//
#include <hip/hip_runtime.h>
#include <math.h>

// TopKSoftMax: rows of D=64 f32; keep top-8 (ties -> lower index, exactly as
// jax.lax.top_k), softmax over kept, zeros elsewhere.
//
// R12 = R10 geometry + register discipline (16-row tiles, 4-wave blocks,
// 32 waves/CU, PROC re-reads LDS, nothing big live across phases) with R11's
// VALU cuts grafted in WITHOUT the register-lifetime mistake:
//  - med3 insert: n0=max(t0,x), n_i=med3(t_{i-1},t_i,x): 8 independent ops
//    (chain depth 1) vs 15 serial. Proved exact by case analysis.
//  - fast PROC: B = m + log(sum); o = (x>=thr) ? exp(x-B) : 0. Exact iff all
//    ==thr elements are kept, tested via (C==qrow && !sat): a chunk's register
//    tie-count can only undercount if its t7==thr (no chunk can hold 8 elems
//    > thr when thr is the union's 8th largest). Rare rows take a slow path
//    with TRUE per-chunk tie counts re-read from LDS (wave-uniform branch).
// R11's regression was scratch spill (v[8]+slot[8] live across everything:
// VGPR 48, WRITE 262->325 MB, FETCH +15 MB) -- NOT the VALU changes.
//
// LDS slot(r,k) = r*16 + (k ^ r) (r<16), float4 units; stage/topk/PROC/out
// all at the structural bank minimum (verified R4-R11). NT stores (R10 win).

#define D4 16
#define ROWS 16
#define TILE_F4 (ROWS * D4)        // 256 float4 = 4 KB
#define WAVES 4
#define THREADS (WAVES * 64)       // 256

typedef float nfloat4 __attribute__((ext_vector_type(4)));

// med3 insert of x into sorted-desc t0>=..>=t7 (keeps top-8 of the 9-multiset)
#define INS(xx) { \
    const float _x = (xx); \
    const float n0 = fmaxf(t0, _x); \
    const float n1 = __builtin_amdgcn_fmed3f(t0, t1, _x); \
    const float n2 = __builtin_amdgcn_fmed3f(t1, t2, _x); \
    const float n3 = __builtin_amdgcn_fmed3f(t2, t3, _x); \
    const float n4 = __builtin_amdgcn_fmed3f(t3, t4, _x); \
    const float n5 = __builtin_amdgcn_fmed3f(t4, t5, _x); \
    const float n6 = __builtin_amdgcn_fmed3f(t5, t6, _x); \
    const float n7 = __builtin_amdgcn_fmed3f(t6, t7, _x); \
    t0 = n0; t1 = n1; t2 = n2; t3 = n3; t4 = n4; t5 = n5; t6 = n6; t7 = n7; }

// compare-exchange, max to first (desc order)
#define CE(a, b) { const float _hi = fmaxf(a, b); b = fminf(a, b); a = _hi; }

// fast path: all ==thr elements kept
#define PROCF(x, o) { (o) = ((x) >= thr) ? __expf((x) - B) : 0.0f; }
// slow path: index-ordered tie quota (quota=999 for fast rows in a slow wave)
#define PROCS(x, o) { \
    const int _k = ((x) == thr) & (quota > 0); \
    quota -= _k; \
    (o) = (((x) > thr) | _k) ? __expf((x) - B) : 0.0f; }

// legacy (tail kernel only)
#define LVL(ti) { const float _hi = fmaxf(ti, _a); _a = fminf(ti, _a); ti = _hi; }
#define INSERT(x) { float _a = (x); \
    LVL(t0) LVL(t1) LVL(t2) LVL(t3) LVL(t4) LVL(t5) LVL(t6) \
    t7 = fmaxf(t7, _a); }
#define PROC(x, o) { \
    const int _kgt = ((x) > thr); \
    const int _keq = ((x) == thr) & (quota > 0); \
    quota -= _keq; \
    (o) = (_kgt | _keq) ? __expf((x) - m) * inv : 0.0f; }

__device__ __forceinline__ void gload_lds16(const void* g, void* l) {
    __builtin_amdgcn_global_load_lds(
        (__attribute__((address_space(1))) void*)(g),
        (__attribute__((address_space(3))) void*)(l),
        16, 0, 0);   // 16B/lane -> global_load_lds_dwordx4
}

__global__ __launch_bounds__(THREADS, 8)   // 8 waves/EU -> 32 waves/CU
void topk_softmax_kernel(const float* __restrict__ in,
                         float* __restrict__ out,
                         int ntiles)
{
    __shared__ float4 tile_[WAVES][TILE_F4];   // 4 KB per wave, private

    const int lane = threadIdx.x & 63;
    const int wid  = threadIdx.x >> 6;
    const int w = blockIdx.x * WAVES + wid;    // one 16-row tile per wave
    if (w >= ntiles) return;
    float4* tile = tile_[wid];

    const float4* __restrict__ p = reinterpret_cast<const float4*>(in) + (long long)w * TILE_F4;
    float4* __restrict__ q       = reinterpret_cast<float4*>(out)      + (long long)w * TILE_F4;

    const int g = lane >> 4;          // 0..3
    const int s = lane & 15;

    // ---- stage: 4x global_load_lds_dwordx4, source pre-swizzled so linear
    //      LDS dest = swizzled tile: slot r*16+(k^r) <- (row r, quad k) ----
    #pragma unroll
    for (int c = 0; c < 4; ++c) {
        const int r = c * 4 + g;
        gload_lds16(p + r * 16 + (s ^ r), tile + c * 64);
    }
    asm volatile("s_waitcnt vmcnt(0)" ::: "memory");

    // ---- per-lane top-8 of its 16 elements (row r2, quads [4h,4h+4)) via
    //      med3 inserts; nothing else kept in registers ----
    const int r2 = lane & 15;
    const int h  = lane >> 4;
    const int qb = h * 4;
    float t0 = -INFINITY, t1 = -INFINITY, t2 = -INFINITY, t3 = -INFINITY,
          t4 = -INFINITY, t5 = -INFINITY, t6 = -INFINITY, t7 = -INFINITY;
    #pragma unroll
    for (int j = 0; j < 4; ++j) {
        const float4 v = tile[r2 * 16 + ((qb + j) ^ r2)];
        INS(v.x) INS(v.y) INS(v.z) INS(v.w)
    }

    // ---- merge chunks h <-> h^1 (xor16): bitonic max-merge + cleanup sort ----
    const float pa0 = __shfl_xor(t0, 16), pa1 = __shfl_xor(t1, 16),
                pa2 = __shfl_xor(t2, 16), pa3 = __shfl_xor(t3, 16),
                pa4 = __shfl_xor(t4, 16), pa5 = __shfl_xor(t5, 16),
                pa6 = __shfl_xor(t6, 16), pa7 = __shfl_xor(t7, 16);
    float c0 = fmaxf(t0, pa7), c1 = fmaxf(t1, pa6), c2 = fmaxf(t2, pa5),
          c3 = fmaxf(t3, pa4), c4 = fmaxf(t4, pa3), c5 = fmaxf(t5, pa2),
          c6 = fmaxf(t6, pa1), c7 = fmaxf(t7, pa0);
    CE(c0, c4) CE(c1, c5) CE(c2, c6) CE(c3, c7)   // bitonic -> sorted desc
    CE(c0, c2) CE(c1, c3) CE(c4, c6) CE(c5, c7)
    CE(c0, c1) CE(c2, c3) CE(c4, c5) CE(c6, c7)

    // ---- merge 32 <-> 32 (xor32): f = top-8 multiset of the row (unsorted ok)
    const float pb0 = __shfl_xor(c0, 32), pb1 = __shfl_xor(c1, 32),
                pb2 = __shfl_xor(c2, 32), pb3 = __shfl_xor(c3, 32),
                pb4 = __shfl_xor(c4, 32), pb5 = __shfl_xor(c5, 32),
                pb6 = __shfl_xor(c6, 32), pb7 = __shfl_xor(c7, 32);
    const float f0 = fmaxf(c0, pb7), f1 = fmaxf(c1, pb6), f2 = fmaxf(c2, pb5),
                f3 = fmaxf(c3, pb4), f4 = fmaxf(c4, pb3), f5 = fmaxf(c5, pb2),
                f6 = fmaxf(c6, pb1), f7 = fmaxf(c7, pb0);

    const float m   = fmaxf(c0, pb0);              // row max
    const float thr = fminf(fminf(fminf(f0, f1), fminf(f2, f3)),
                            fminf(fminf(f4, f5), fminf(f6, f7)));   // 8th largest
    const int cnt_gt = (f0 > thr) + (f1 > thr) + (f2 > thr) + (f3 > thr) +
                       (f4 > thr) + (f5 > thr) + (f6 > thr) + (f7 > thr);
    const float sum = __expf(f0 - m) + __expf(f1 - m) + __expf(f2 - m) + __expf(f3 - m) +
                      __expf(f4 - m) + __expf(f5 - m) + __expf(f6 - m) + __expf(f7 - m);
    const float B = m + __logf(sum);   // exp(x-m)/sum == exp(x-B)
    const int qrow = 8 - cnt_gt;

    // ---- fast/slow decision: counted ties (register) + saturation flags,
    //      reduced over the row's 4 chunk-lanes; row-uniform result ----
    const int ce8 = (t0 == thr) + (t1 == thr) + (t2 == thr) + (t3 == thr) +
                    (t4 == thr) + (t5 == thr) + (t6 == thr) + (t7 == thr);
    const int pack = ce8 | ((t7 == thr) ? 256 : 0);
    const int v1 = pack + __shfl_xor(pack, 16);
    const int v2 = v1 + __shfl_xor(v1, 32);
    const bool slow = ((v2 & 255) != qrow) | (v2 >> 8);

    if (!__any(slow)) {
        // ---- fast PROC: re-read own quads from LDS, write back in place ----
        #pragma unroll
        for (int j = 0; j < 4; ++j) {
            const int slot = r2 * 16 + ((qb + j) ^ r2);
            const float4 v = tile[slot];
            float4 o;
            PROCF(v.x, o.x) PROCF(v.y, o.y) PROCF(v.z, o.z) PROCF(v.w, o.w)
            tile[slot] = o;
        }
    } else {
        // ---- rare: exact sequential tie quota with TRUE per-chunk counts ----
        float4 vv[4];
        int my_eq = 0;
        #pragma unroll
        for (int j = 0; j < 4; ++j) {
            vv[j] = tile[r2 * 16 + ((qb + j) ^ r2)];
            my_eq += (vv[j].x == thr) + (vv[j].y == thr) +
                     (vv[j].z == thr) + (vv[j].w == thr);
        }
        const int e1 = __shfl_xor(my_eq, 16);     // eq(h^1)
        const int e2 = __shfl_xor(my_eq, 32);     // eq(h^2)
        const int e3 = __shfl_xor(e1, 32);        // eq(h^3)
        const int a0 = (h == 0) ? my_eq : (h == 1) ? e1 : (h == 2) ? e2 : e3;
        const int a1 = (h == 1) ? my_eq : (h == 0) ? e1 : (h == 3) ? e2 : e3;
        const int a2 = (h == 2) ? my_eq : (h == 3) ? e1 : (h == 0) ? e2 : e3;
        const int pre = (h > 0 ? a0 : 0) + (h > 1 ? a1 : 0) + (h > 2 ? a2 : 0);
        int quota = slow ? (qrow - pre) : 999;    // fast rows keep all ties
        #pragma unroll
        for (int j = 0; j < 4; ++j) {
            const int slot = r2 * 16 + ((qb + j) ^ r2);
            float4 o;
            PROCS(vv[j].x, o.x) PROCS(vv[j].y, o.y)
            PROCS(vv[j].z, o.z) PROCS(vv[j].w, o.w)
            tile[slot] = o;
        }
    }
    asm volatile("s_waitcnt lgkmcnt(0)" ::: "memory");   // cross-lane reuse below

    // ---- coalesced NT out: flat F=c*64+lane lives at slot r*16+((lane&15)^r) ----
    #pragma unroll
    for (int c = 0; c < 4; ++c) {
        const int r = c * 4 + g;
        const float4 o = tile[r * 16 + (s ^ r)];
        nfloat4 no; no.x = o.x; no.y = o.y; no.z = o.z; no.w = o.w;
        __builtin_nontemporal_store(no,
            reinterpret_cast<nfloat4*>(q + c * 64 + lane));
    }
}

// remainder rows (nrows % 16) — not taken at this problem size
__global__ __launch_bounds__(64)
void topk_softmax_tail(const float* __restrict__ in, float* __restrict__ out,
                       long long row0, long long nrows)
{
    const long long row = row0 + threadIdx.x;
    if (row >= nrows) return;
    const float4* __restrict__ p = reinterpret_cast<const float4*>(in) + row * D4;
    float4* __restrict__ q       = reinterpret_cast<float4*>(out)      + row * D4;
    float4 v[D4];
    #pragma unroll
    for (int c = 0; c < D4; ++c) v[c] = p[c];
    float t0 = -INFINITY, t1 = -INFINITY, t2 = -INFINITY, t3 = -INFINITY,
          t4 = -INFINITY, t5 = -INFINITY, t6 = -INFINITY, t7 = -INFINITY;
    #pragma unroll
    for (int c = 0; c < D4; ++c) {
        INSERT(v[c].x) INSERT(v[c].y) INSERT(v[c].z) INSERT(v[c].w)
    }
    const float thr = t7;
    const float m   = t0;
    int quota = 8 - ((t0 > thr) + (t1 > thr) + (t2 > thr) + (t3 > thr) +
                     (t4 > thr) + (t5 > thr) + (t6 > thr));
    const float sum = __expf(t0 - m) + __expf(t1 - m) + __expf(t2 - m) + __expf(t3 - m) +
                      __expf(t4 - m) + __expf(t5 - m) + __expf(t6 - m) + __expf(t7 - m);
    const float inv = 1.0f / sum;
    #pragma unroll
    for (int c = 0; c < D4; ++c) {
        float4 o;
        PROC(v[c].x, o.x) PROC(v[c].y, o.y) PROC(v[c].z, o.z) PROC(v[c].w, o.w)
        q[c] = o;
    }
}

extern "C" void kernel_launch(void* const* d_in, const int* in_sizes, int n_in,
                              void* d_out, int out_size, void* d_ws, size_t ws_size,
                              hipStream_t stream) {
    const float* in = (const float*)d_in[0];
    float* out = (float*)d_out;
    const long long nrows = in_sizes[0] / 64;
    const int ntiles = (int)(nrows / ROWS);
    const long long rem = nrows - (long long)ntiles * ROWS;

    if (ntiles > 0) {
        const int nblocks = (ntiles + WAVES - 1) / WAVES;
        topk_softmax_kernel<<<nblocks, THREADS, 0, stream>>>(in, out, ntiles);
    }
    if (rem > 0) {
        topk_softmax_tail<<<1, 64, 0, stream>>>(in, out, (long long)ntiles * ROWS, nrows);
    }
}